// Round 1
// baseline (1785.629 us; speedup 1.0000x reference)
//
#include <hip/hip_runtime.h>
#include <hip/hip_bf16.h>

// Problem constants: B=4, S=2048, E=1024, H=16, DH=64. causal==1 always.
typedef __bf16 bf16;
typedef __bf16 bf16x4 __attribute__((ext_vector_type(4)));
typedef __bf16 bf16x8 __attribute__((ext_vector_type(8)));
typedef float f32x4 __attribute__((ext_vector_type(4)));

constexpr int Bc = 4, Sc = 2048, Ec = 1024, Hc = 16, DHc = 64;
constexpr int MBS = Bc * Sc;              // 8192 rows for all projections
constexpr size_t NE = (size_t)MBS * Ec;   // 8,388,608 elements

// ---------------------------------------------------------------------------
// GEMM (B-transposed): C[m,n] = sum_k A[m,k] * W[n,k] + bias[n]
// M=8192, N=1024, K=1024. 128x128 tile, BK=32, 4 waves 2x2, 4x4 16x16x32 MFMA.
// (unchanged from previous verified version)
// ---------------------------------------------------------------------------
template<typename AT, bool OUT_BF16>
__global__ __launch_bounds__(256) void gemm_bt_kernel(
    const AT* __restrict__ A, const float* __restrict__ W,
    const float* __restrict__ bias, void* __restrict__ Cout)
{
  __shared__ bf16 As[128][40];  // +8 pad: 80B rows -> 2-way banks (free)
  __shared__ bf16 Ws[128][40];
  const int tid  = threadIdx.x;
  const int wave = tid >> 6, lane = tid & 63;
  const int quad = lane >> 4, l16 = lane & 15;
  const int wm = (wave & 1) * 64, wn = (wave >> 1) * 64;
  const int m0 = blockIdx.y * 128, n0 = blockIdx.x * 128;
  f32x4 acc[4][4] = {};

  for (int k0 = 0; k0 < 1024; k0 += 32) {
    __syncthreads();
    if constexpr (sizeof(AT) == 4) {
      const int r = tid >> 3, c = (tid & 7) * 4;
#pragma unroll
      for (int p = 0; p < 4; ++p) {
        const float4 v = *(const float4*)&A[(size_t)(m0 + r + 32 * p) * 1024 + k0 + c];
        bf16x4 bv = { (bf16)v.x, (bf16)v.y, (bf16)v.z, (bf16)v.w };
        *(bf16x4*)&As[r + 32 * p][c] = bv;
      }
    } else {
      const int r = tid >> 1, c = (tid & 1) * 16;
      const uint4 v0 = *(const uint4*)&A[(size_t)(m0 + r) * 1024 + k0 + c];
      const uint4 v1 = *(const uint4*)&A[(size_t)(m0 + r) * 1024 + k0 + c + 8];
      *(uint4*)&As[r][c]     = v0;
      *(uint4*)&As[r][c + 8] = v1;
    }
    {
      const int r = tid >> 3, c = (tid & 7) * 4;
#pragma unroll
      for (int p = 0; p < 4; ++p) {
        const float4 v = *(const float4*)&W[(size_t)(n0 + r + 32 * p) * 1024 + k0 + c];
        bf16x4 bv = { (bf16)v.x, (bf16)v.y, (bf16)v.z, (bf16)v.w };
        *(bf16x4*)&Ws[r + 32 * p][c] = bv;
      }
    }
    __syncthreads();
    bf16x8 af[4], bg[4];
#pragma unroll
    for (int i = 0; i < 4; ++i)
      af[i] = *(const bf16x8*)&As[wm + i * 16 + l16][quad * 8];
#pragma unroll
    for (int j = 0; j < 4; ++j)
      bg[j] = *(const bf16x8*)&Ws[wn + j * 16 + l16][quad * 8];
#pragma unroll
    for (int i = 0; i < 4; ++i)
#pragma unroll
      for (int j = 0; j < 4; ++j)
        acc[i][j] = __builtin_amdgcn_mfma_f32_16x16x32_bf16(af[i], bg[j], acc[i][j], 0, 0, 0);
  }

#pragma unroll
  for (int j = 0; j < 4; ++j) {
    const int col = n0 + wn + j * 16 + l16;
    const float bv = bias[col];
#pragma unroll
    for (int i = 0; i < 4; ++i) {
      const int rowb = m0 + wm + i * 16 + quad * 4;
#pragma unroll
      for (int r = 0; r < 4; ++r) {
        const float v = acc[i][j][r] + bv;
        if constexpr (OUT_BF16)
          ((bf16*)Cout)[(size_t)(rowb + r) * 1024 + col] = (bf16)v;
        else
          ((float*)Cout)[(size_t)(rowb + r) * 1024 + col] = v;
      }
    }
  }
}

// ---------------------------------------------------------------------------
// Fused attention: per (bh, 128-row tile).
//   Loop 1: recomputable QK^T tiles -> online row max m / sumexp l (registers).
//   Merge col-halves through tiny LDS buffer.
//   Loop 2: recompute tile, p = exp((s-m)*0.125)/l, write final attn (the one
//           mandatory 1.07 GB write), read the just-written 64 KB tile back
//           (L2/L1 hit after __syncthreads drain) and accumulate PV via MFMA.
//   Upper-triangle zero tiles written at the end by the same block.
// Replaces scores_kernel + softmax_kernel + pv_kernel (saves ~1.6 GB HBM).
// ---------------------------------------------------------------------------
__global__ __launch_bounds__(256) void fused_attn_kernel(
    const bf16* __restrict__ Qp, const bf16* __restrict__ Kp,
    const bf16* __restrict__ Vp, float* __restrict__ attn,
    bf16* __restrict__ Op)
{
  const int bh = blockIdx.x;
  const int tr = 15 - (int)blockIdx.y;  // heavy (diagonal-rich) blocks first
  const int b = bh >> 4, h = bh & 15;
  const int row0 = tr * 128;
  float* __restrict__ out = attn + (size_t)bh * Sc * Sc;
  const size_t hoff = (size_t)b * Sc * Ec + (size_t)h * 64;
  const bf16* __restrict__ Vh = Vp + hoff;
  bf16* __restrict__ Oh = Op + hoff;

  __shared__ bf16 Qs[128][72];     // Q tile, staged once
  __shared__ bf16 Ks[128][72];     // K tile, per tc (both loops)
  __shared__ bf16 Ps[128][40];     // P sub-tile (bf16) for PV MFMA
  __shared__ bf16 Vt[64][40];      // V transposed sub-tile
  __shared__ float sred[2][2][128]; // [m|l][colgroup][row] for stats merge

  const int tid = threadIdx.x;
  const int wave = tid >> 6, lane = tid & 63;
  const int quad = lane >> 4, l16 = lane & 15;
  const int wm = (wave & 1) * 64, wn = (wave >> 1) * 64;    // scores layout
  const int wmO = (wave & 1) * 64, wnO = (wave >> 1) * 32;  // PV layout

  // ---- stage Q tile (rows row0..row0+127 of this head) ----
#pragma unroll
  for (int p = 0; p < 4; ++p) {
    const int c = tid + 256 * p;
    const int r = c >> 3, ch = (c & 7) * 8;
    *(uint4*)&Qs[r][ch] = *(const uint4*)&Qp[hoff + (size_t)(row0 + r) * Ec + ch];
  }

  // per-lane row stats: rows wm + i*16 + quad*4 + r (redundant across l16)
  float m_r[4][4], l_r[4][4];
#pragma unroll
  for (int i = 0; i < 4; ++i)
#pragma unroll
    for (int r = 0; r < 4; ++r) { m_r[i][r] = -3.4e38f; l_r[i][r] = 0.f; }

  // ================= loop 1: online row max / sumexp =================
  for (int tc = 0; tc <= tr; ++tc) {
    const int col0 = tc * 128;
    __syncthreads();
#pragma unroll
    for (int p = 0; p < 4; ++p) {
      const int c = tid + 256 * p;
      const int r = c >> 3, ch = (c & 7) * 8;
      *(uint4*)&Ks[r][ch] = *(const uint4*)&Kp[hoff + (size_t)(col0 + r) * Ec + ch];
    }
    __syncthreads();
    f32x4 accs[4][4] = {};
#pragma unroll
    for (int kk = 0; kk < 2; ++kk) {
      bf16x8 af[4], bg[4];
#pragma unroll
      for (int i = 0; i < 4; ++i)
        af[i] = *(const bf16x8*)&Qs[wm + i * 16 + l16][kk * 32 + quad * 8];
#pragma unroll
      for (int j = 0; j < 4; ++j)
        bg[j] = *(const bf16x8*)&Ks[wn + j * 16 + l16][kk * 32 + quad * 8];
#pragma unroll
      for (int i = 0; i < 4; ++i)
#pragma unroll
        for (int j = 0; j < 4; ++j)
          accs[i][j] = __builtin_amdgcn_mfma_f32_16x16x32_bf16(af[i], bg[j], accs[i][j], 0, 0, 0);
    }
    if (tc == tr) {  // causal mask inside diagonal tile (sentinel; exp->0)
#pragma unroll
      for (int i = 0; i < 4; ++i)
#pragma unroll
        for (int j = 0; j < 4; ++j) {
          const int tcol = wn + j * 16 + l16;
#pragma unroll
          for (int r = 0; r < 4; ++r)
            if (tcol > wm + i * 16 + quad * 4 + r) accs[i][j][r] = -3.4e38f;
        }
    }
    // online update per (i,r): reduce over 4 j-frags + 16 l16 lanes = 64 cols
#pragma unroll
    for (int i = 0; i < 4; ++i)
#pragma unroll
      for (int r = 0; r < 4; ++r) {
        float tm = fmaxf(fmaxf(accs[i][0][r], accs[i][1][r]),
                         fmaxf(accs[i][2][r], accs[i][3][r]));
#pragma unroll
        for (int off = 1; off < 16; off <<= 1)
          tm = fmaxf(tm, __shfl_xor(tm, off, 64));
        const float mo = m_r[i][r];
        const float mn = fmaxf(mo, tm);
        float s = 0.f;
#pragma unroll
        for (int j = 0; j < 4; ++j)
          s += __expf((accs[i][j][r] - mn) * 0.125f);
#pragma unroll
        for (int off = 1; off < 16; off <<= 1)
          s += __shfl_xor(s, off, 64);
        // fully-masked sentinel groups self-correct: rescale factor hits 0
        l_r[i][r] = l_r[i][r] * __expf((mo - mn) * 0.125f) + s;
        m_r[i][r] = mn;
      }
  }

  // ---- merge the two 64-col wave groups per row ----
  {
    const int cg = wave >> 1;
    if (l16 == 0) {
#pragma unroll
      for (int i = 0; i < 4; ++i)
#pragma unroll
        for (int r = 0; r < 4; ++r) {
          const int row = wm + i * 16 + quad * 4 + r;
          sred[0][cg][row] = m_r[i][r];
          sred[1][cg][row] = l_r[i][r];
        }
    }
    __syncthreads();
#pragma unroll
    for (int i = 0; i < 4; ++i)
#pragma unroll
      for (int r = 0; r < 4; ++r) {
        const int row = wm + i * 16 + quad * 4 + r;
        const float m0 = sred[0][0][row], m1 = sred[0][1][row];
        const float l0 = sred[1][0][row], l1 = sred[1][1][row];
        const float mn = fmaxf(m0, m1);
        const float l = l0 * __expf((m0 - mn) * 0.125f)
                      + l1 * __expf((m1 - mn) * 0.125f);
        m_r[i][r] = mn;
        l_r[i][r] = 1.f / l;  // now holds inverse denominator
      }
  }

  // ================= loop 2: emit attn + accumulate PV =================
  f32x4 acc_o[4][2] = {};
  for (int tc = 0; tc <= tr; ++tc) {
    const int col0 = tc * 128;
    __syncthreads();
#pragma unroll
    for (int p = 0; p < 4; ++p) {
      const int c = tid + 256 * p;
      const int r = c >> 3, ch = (c & 7) * 8;
      *(uint4*)&Ks[r][ch] = *(const uint4*)&Kp[hoff + (size_t)(col0 + r) * Ec + ch];
    }
    __syncthreads();
    f32x4 accs[4][4] = {};
#pragma unroll
    for (int kk = 0; kk < 2; ++kk) {
      bf16x8 af[4], bg[4];
#pragma unroll
      for (int i = 0; i < 4; ++i)
        af[i] = *(const bf16x8*)&Qs[wm + i * 16 + l16][kk * 32 + quad * 8];
#pragma unroll
      for (int j = 0; j < 4; ++j)
        bg[j] = *(const bf16x8*)&Ks[wn + j * 16 + l16][kk * 32 + quad * 8];
#pragma unroll
      for (int i = 0; i < 4; ++i)
#pragma unroll
        for (int j = 0; j < 4; ++j)
          accs[i][j] = __builtin_amdgcn_mfma_f32_16x16x32_bf16(af[i], bg[j], accs[i][j], 0, 0, 0);
    }
    // normalize + final attn write (the only HBM pass over attn)
#pragma unroll
    for (int i = 0; i < 4; ++i)
#pragma unroll
      for (int j = 0; j < 4; ++j) {
        const int col = col0 + wn + j * 16 + l16;
#pragma unroll
        for (int r = 0; r < 4; ++r) {
          const int row = row0 + wm + i * 16 + quad * 4 + r;
          float p = __expf((accs[i][j][r] - m_r[i][r]) * 0.125f) * l_r[i][r];
          if (col > row) p = 0.f;  // only bites on the diagonal tile
          out[(size_t)row * Sc + col] = p;
        }
      }
    // PV over this 128-col tile; P read back from just-written attn (L2-hot).
    // First __syncthreads drains vmcnt(0) -> all waves' p stores visible.
#pragma unroll 1
    for (int kk0 = 0; kk0 < 128; kk0 += 32) {
      const int k0 = col0 + kk0;
      __syncthreads();
      {
        const int r = tid >> 3, c = (tid & 7) * 4;
#pragma unroll
        for (int p = 0; p < 4; ++p) {
          const float4 v = *(const float4*)&out[(size_t)(row0 + r + 32 * p) * Sc + k0 + c];
          bf16x4 bv = { (bf16)v.x, (bf16)v.y, (bf16)v.z, (bf16)v.w };
          *(bf16x4*)&Ps[r + 32 * p][c] = bv;
        }
      }
      {
        const int kk = tid >> 3, nn = (tid & 7) * 8;
        const uint4 raw = *(const uint4*)&Vh[(size_t)(k0 + kk) * Ec + nn];
        const bf16* pv = reinterpret_cast<const bf16*>(&raw);
#pragma unroll
        for (int jj = 0; jj < 8; ++jj) Vt[nn + jj][kk] = pv[jj];
      }
      __syncthreads();
      bf16x8 paf[4], pbg[2];
#pragma unroll
      for (int i = 0; i < 4; ++i)
        paf[i] = *(const bf16x8*)&Ps[wmO + i * 16 + l16][quad * 8];
#pragma unroll
      for (int j = 0; j < 2; ++j)
        pbg[j] = *(const bf16x8*)&Vt[wnO + j * 16 + l16][quad * 8];
#pragma unroll
      for (int i = 0; i < 4; ++i)
#pragma unroll
        for (int j = 0; j < 2; ++j)
          acc_o[i][j] = __builtin_amdgcn_mfma_f32_16x16x32_bf16(paf[i], pbg[j], acc_o[i][j], 0, 0, 0);
    }
  }

  // ---- write O tile (bf16, feeds final projection GEMM) ----
#pragma unroll
  for (int j = 0; j < 2; ++j) {
    const int col = wnO + j * 16 + l16;
#pragma unroll
    for (int i = 0; i < 4; ++i) {
      const int rowb = row0 + wmO + i * 16 + quad * 4;
#pragma unroll
      for (int r = 0; r < 4; ++r)
        Oh[(size_t)(rowb + r) * Ec + col] = (bf16)acc_o[i][j][r];
    }
  }

  // ---- zero-fill masked upper tiles (covers 0xAA poison) ----
  {
    const int r = tid >> 1, cb = (tid & 1) * 64;
    const float4 z = {0.f, 0.f, 0.f, 0.f};
    for (int tc2 = tr + 1; tc2 < 16; ++tc2) {
      const int col0 = tc2 * 128;
#pragma unroll
      for (int q = 0; q < 16; ++q)
        *(float4*)&out[(size_t)(row0 + r) * Sc + col0 + cb + q * 4] = z;
    }
  }
}

// ---------------------------------------------------------------------------
extern "C" void kernel_launch(void* const* d_in, const int* in_sizes, int n_in,
                              void* d_out, int out_size, void* d_ws, size_t ws_size,
                              hipStream_t stream) {
  (void)in_sizes; (void)n_in; (void)out_size; (void)ws_size;
  const float* q  = (const float*)d_in[0];
  const float* k  = (const float*)d_in[1];
  const float* v  = (const float*)d_in[2];
  const float* wq = (const float*)d_in[3];
  const float* bq = (const float*)d_in[4];
  const float* wk = (const float*)d_in[5];
  const float* bk = (const float*)d_in[6];
  const float* wv = (const float*)d_in[7];
  const float* bv = (const float*)d_in[8];
  const float* wo = (const float*)d_in[9];
  const float* bo = (const float*)d_in[10];
  // causal flag (d_in[11]) is always 1 for this problem; hardcoded.

  float* out  = (float*)d_out;
  float* attn = out + NE;  // [B,H,S,S] fp32

  bf16* wsQ = (bf16*)d_ws;           // [8192,1024] bf16 each
  bf16* wsK = wsQ + NE;
  bf16* wsV = wsK + NE;
  bf16* wsO = wsV + NE;

  const dim3 gP(8, 64);  // N/128, M/128
  gemm_bt_kernel<float, true><<<gP, 256, 0, stream>>>(q, wq, bq, wsQ);
  gemm_bt_kernel<float, true><<<gP, 256, 0, stream>>>(k, wk, bk, wsK);
  gemm_bt_kernel<float, true><<<gP, 256, 0, stream>>>(v, wv, bv, wsV);

  // fused scores+softmax+PV: grid x = bh (uniform work per dispatch wave),
  // y = row tile (reversed so diagonal-heavy blocks launch first)
  fused_attn_kernel<<<dim3(64, 16), 256, 0, stream>>>(wsQ, wsK, wsV, attn, wsO);

  gemm_bt_kernel<__bf16, false><<<gP, 256, 0, stream>>>(wsO, wo, bo, out);
}

// Round 2
// 1395.854 us; speedup vs baseline: 1.2792x; 1.2792x over previous
//
#include <hip/hip_runtime.h>
#include <hip/hip_bf16.h>

// Problem constants: B=4, S=2048, E=1024, H=16, DH=64. causal==1 always.
typedef __bf16 bf16;
typedef __bf16 bf16x4 __attribute__((ext_vector_type(4)));
typedef __bf16 bf16x8 __attribute__((ext_vector_type(8)));
typedef float f32x4 __attribute__((ext_vector_type(4)));

constexpr int Bc = 4, Sc = 2048, Ec = 1024, Hc = 16, DHc = 64;
constexpr int MBS = Bc * Sc;              // 8192 rows for all projections
constexpr size_t NE = (size_t)MBS * Ec;   // 8,388,608 elements
constexpr size_t EE = (size_t)Ec * Ec;    // 1,048,576 (weight elems)

// Async global->LDS, 16B per lane, wave-uniform LDS base + lane*16.
__device__ __forceinline__ void gload16(const bf16* g, bf16* l) {
  __builtin_amdgcn_global_load_lds(
      (const __attribute__((address_space(1))) void*)g,
      (__attribute__((address_space(3))) void*)l, 16, 0, 0);
}

// ---------------------------------------------------------------------------
// fp32 -> bf16 converters (one-shot; feeds all GEMMs with bf16 operands)
// ---------------------------------------------------------------------------
__global__ __launch_bounds__(256) void cvt_all_kernel(
    const float* __restrict__ q, const float* __restrict__ k,
    const float* __restrict__ v, const float* __restrict__ wq,
    const float* __restrict__ wk, const float* __restrict__ wv,
    bf16* __restrict__ qb, bf16* __restrict__ kb, bf16* __restrict__ vb,
    bf16* __restrict__ wqb, bf16* __restrict__ wkb, bf16* __restrict__ wvb)
{
  const int g = blockIdx.x;  // 12288 big + 1536 small = 13824
  const float* s; bf16* d; size_t off;
  if (g < 12288) {
    const int t = g >> 12;
    s = (t == 0) ? q : (t == 1) ? k : v;
    d = (t == 0) ? qb : (t == 1) ? kb : vb;
    off = (size_t)(g & 4095) * 2048;
  } else {
    const int t = (g - 12288) >> 9;
    s = (t == 0) ? wq : (t == 1) ? wk : wv;
    d = (t == 0) ? wqb : (t == 1) ? wkb : wvb;
    off = (size_t)((g - 12288) & 511) * 2048;
  }
  const size_t i = off + (size_t)threadIdx.x * 8;
  const float4 a = *(const float4*)&s[i];
  const float4 b = *(const float4*)&s[i + 4];
  bf16x8 o = { (bf16)a.x, (bf16)a.y, (bf16)a.z, (bf16)a.w,
               (bf16)b.x, (bf16)b.y, (bf16)b.z, (bf16)b.w };
  *(bf16x8*)&d[i] = o;
}

__global__ __launch_bounds__(256) void cvt_one_kernel(
    const float* __restrict__ s, bf16* __restrict__ d)
{
  const size_t i = (size_t)blockIdx.x * 2048 + (size_t)threadIdx.x * 8;
  const float4 a = *(const float4*)&s[i];
  const float4 b = *(const float4*)&s[i + 4];
  bf16x8 o = { (bf16)a.x, (bf16)a.y, (bf16)a.z, (bf16)a.w,
               (bf16)b.x, (bf16)b.y, (bf16)b.z, (bf16)b.w };
  *(bf16x8*)&d[i] = o;
}

// ---------------------------------------------------------------------------
// GEMM (B-transposed), all-bf16 inputs: C[m,n] = sum_k A[m,k]*W[n,k] + bias[n]
// M=8192 (x64 tiles), N=1024 (x8 tiles). m97 structure: 128x128 tile, BK=64,
// global_load_lds 16B staging into linear LDS, XOR-swizzled fragment reads,
// XCD-chunked block swizzle (512 blocks, 64 per XCD sharing 8 m-panels).
// ---------------------------------------------------------------------------
template<bool OUT_BF16>
__global__ __launch_bounds__(256, 2) void gemm_bt_bf16(
    const bf16* __restrict__ A, const bf16* __restrict__ W,
    const float* __restrict__ bias, void* __restrict__ Cout)
{
  __shared__ bf16 As[128][64];
  __shared__ bf16 Ws[128][64];
  const int tid  = threadIdx.x;
  const int wave = tid >> 6, lane = tid & 63;
  const int quad = lane >> 4, l16 = lane & 15;
  const int lr = lane >> 3, lc = lane & 7;   // staging row-in-8, 16B chunk
  const int wm = (wave & 1) * 64, wn = (wave >> 1) * 64;
  const int gg = blockIdx.x;                  // 512 flat
  const int m0 = ((gg & 7) * 8 + ((gg >> 3) >> 3)) * 128;
  const int n0 = ((gg >> 3) & 7) * 128;
  f32x4 acc[4][4] = {};

  for (int k0 = 0; k0 < 1024; k0 += 64) {
    __syncthreads();
#pragma unroll
    for (int c = 0; c < 4; ++c) {
      const int row = wave * 32 + c * 8 + lr;
      gload16(A + (size_t)(m0 + row) * 1024 + k0 + ((lc ^ lr) << 3),
              &As[wave * 32 + c * 8][0]);
      gload16(W + (size_t)(n0 + row) * 1024 + k0 + ((lc ^ lr) << 3),
              &Ws[wave * 32 + c * 8][0]);
    }
    __syncthreads();
#pragma unroll
    for (int kk = 0; kk < 2; ++kk) {
      bf16x8 af[4], bg[4];
#pragma unroll
      for (int i = 0; i < 4; ++i) {
        const int row = wm + i * 16 + l16;
        af[i] = *(const bf16x8*)&As[row][((((kk << 2) + quad) ^ (row & 7)) << 3)];
      }
#pragma unroll
      for (int j = 0; j < 4; ++j) {
        const int row = wn + j * 16 + l16;
        bg[j] = *(const bf16x8*)&Ws[row][((((kk << 2) + quad) ^ (row & 7)) << 3)];
      }
#pragma unroll
      for (int i = 0; i < 4; ++i)
#pragma unroll
        for (int j = 0; j < 4; ++j)
          acc[i][j] = __builtin_amdgcn_mfma_f32_16x16x32_bf16(af[i], bg[j], acc[i][j], 0, 0, 0);
    }
  }

#pragma unroll
  for (int j = 0; j < 4; ++j) {
    const int col = n0 + wn + j * 16 + l16;
    const float bv = bias[col];
#pragma unroll
    for (int i = 0; i < 4; ++i) {
      const int rowb = m0 + wm + i * 16 + quad * 4;
#pragma unroll
      for (int r = 0; r < 4; ++r) {
        const float v = acc[i][j][r] + bv;
        if constexpr (OUT_BF16)
          ((bf16*)Cout)[(size_t)(rowb + r) * 1024 + col] = (bf16)v;
        else
          ((float*)Cout)[(size_t)(rowb + r) * 1024 + col] = v;
      }
    }
  }
}

// ---------------------------------------------------------------------------
// Fused attention per (bh, 128-row tile), swapped-operand MFMA throughout.
// QK^T computed as mfma(K,Q): lane holds S[qrow = base+l16][kcol = quad*4+r]
//  -> float4 attn stores, 2-shuffle row reduces, b64 P->LDS writes.
// Loop1: online (m,l) in registers. Merge halves via tiny LDS.
// Loop2: recompute, p=exp((s-m)/8)/l -> nontemporal float4 attn write + b64
//        LDS P write; PV = mfma(V,P) (O^T layout -> b64 O stores). P never
//        round-trips through global. 3 barriers per K-tile.
// ---------------------------------------------------------------------------
__global__ __launch_bounds__(256, 2) void fused_attn_kernel(
    const bf16* __restrict__ Qp, const bf16* __restrict__ Kp,
    const bf16* __restrict__ Vp, float* __restrict__ attn,
    bf16* __restrict__ Op)
{
  // XCD-chunked swizzle: 1024 blocks; xcd = g&7 owns bh group xcd*8..+7.
  const int g   = blockIdx.x;
  const int idx = g >> 3;
  const int bh  = (g & 7) * 8 + (idx >> 4);
  const int tr  = 15 - (idx & 15);          // heavy (diagonal-rich) first
  const int b = bh >> 4, h = bh & 15;
  const int row0 = tr * 128;
  float* __restrict__ out = attn + (size_t)bh * Sc * Sc;
  const size_t hoff = (size_t)b * Sc * Ec + (size_t)h * DHc;
  const bf16* __restrict__ Vh = Vp + hoff;
  bf16* __restrict__ Oh = Op + hoff;

  __shared__ bf16 Ks[128][64];     // linear, gload_lds staged, swz reads
  __shared__ bf16 Ps[128][128];    // XOR-swizzled P (also stages Q at start)
  __shared__ bf16 Vt[64][136];     // V transposed [n][k], padded stride
  __shared__ float sred[2][2][128];

  const int tid  = threadIdx.x;
  const int wave = tid >> 6, lane = tid & 63;
  const int quad = lane >> 4, l16 = lane & 15;
  const int lr = lane >> 3, lc = lane & 7;
  const int wqm = (wave & 1) * 64;          // Q-row group (QK and PV)
  const int wkn = (wave >> 1) * 64;         // K-col group (QK)
  const int wnO = (wave >> 1) * 32;         // O-col group (PV)

  // ---- stage Q tile into Ps area (linear [128][64]), then into registers ----
  bf16* PsQ = &Ps[0][0];
#pragma unroll
  for (int c = 0; c < 4; ++c) {
    const int row = wave * 32 + c * 8 + lr;
    gload16(Qp + hoff + (size_t)(row0 + row) * Ec + ((lc ^ lr) << 3),
            PsQ + (size_t)(wave * 32 + c * 8) * 64);
  }
  __syncthreads();
  bf16x8 qf[4][2];
#pragma unroll
  for (int i = 0; i < 4; ++i)
#pragma unroll
    for (int kk = 0; kk < 2; ++kk) {
      const int row = wqm + i * 16 + l16;
      qf[i][kk] = *(const bf16x8*)(PsQ + (size_t)row * 64 +
                                   ((((kk << 2) + quad) ^ (row & 7)) << 3));
    }

  float m_r[4], l_r[4];
#pragma unroll
  for (int i = 0; i < 4; ++i) { m_r[i] = -3.4e38f; l_r[i] = 0.f; }

  // ================= loop 1: online row max / sumexp =================
  for (int tc = 0; tc <= tr; ++tc) {
    const int col0 = tc * 128;
    __syncthreads();
#pragma unroll
    for (int c = 0; c < 4; ++c) {
      const int row = wave * 32 + c * 8 + lr;
      gload16(Kp + hoff + (size_t)(col0 + row) * Ec + ((lc ^ lr) << 3),
              &Ks[wave * 32 + c * 8][0]);
    }
    __syncthreads();
    f32x4 sc[4][4] = {};
#pragma unroll
    for (int kk = 0; kk < 2; ++kk) {
      bf16x8 kf[4];
#pragma unroll
      for (int j = 0; j < 4; ++j) {
        const int row = wkn + j * 16 + l16;
        kf[j] = *(const bf16x8*)&Ks[row][((((kk << 2) + quad) ^ (row & 7)) << 3)];
      }
#pragma unroll
      for (int i = 0; i < 4; ++i)
#pragma unroll
        for (int j = 0; j < 4; ++j)
          sc[i][j] = __builtin_amdgcn_mfma_f32_16x16x32_bf16(kf[j], qf[i][kk], sc[i][j], 0, 0, 0);
    }
    if (tc == tr) {  // causal mask inside diagonal tile
#pragma unroll
      for (int i = 0; i < 4; ++i) {
        const int row_t = wqm + i * 16 + l16;
#pragma unroll
        for (int j = 0; j < 4; ++j) {
          const int colb = wkn + j * 16 + quad * 4;
#pragma unroll
          for (int r = 0; r < 4; ++r)
            if (colb + r > row_t) sc[i][j][r] = -3.4e38f;
        }
      }
    }
#pragma unroll
    for (int i = 0; i < 4; ++i) {
      float tm = sc[i][0][0];
#pragma unroll
      for (int j = 0; j < 4; ++j)
#pragma unroll
        for (int r = 0; r < 4; ++r) tm = fmaxf(tm, sc[i][j][r]);
      tm = fmaxf(tm, __shfl_xor(tm, 16, 64));   // cross-quad: full 64-col max
      tm = fmaxf(tm, __shfl_xor(tm, 32, 64));
      const float mn = fmaxf(m_r[i], tm);
      float s = 0.f;
#pragma unroll
      for (int j = 0; j < 4; ++j)
#pragma unroll
        for (int r = 0; r < 4; ++r) s += __expf((sc[i][j][r] - mn) * 0.125f);
      s += __shfl_xor(s, 16, 64);
      s += __shfl_xor(s, 32, 64);
      l_r[i] = l_r[i] * __expf((m_r[i] - mn) * 0.125f) + s;
      m_r[i] = mn;
    }
  }

  // ---- merge the two 64-col halves per row (all-masked halves self-zero) ----
  {
    const int cg = wave >> 1;
    if (quad == 0) {
#pragma unroll
      for (int i = 0; i < 4; ++i) {
        const int row = wqm + i * 16 + l16;
        sred[0][cg][row] = m_r[i];
        sred[1][cg][row] = l_r[i];
      }
    }
    __syncthreads();
#pragma unroll
    for (int i = 0; i < 4; ++i) {
      const int row = wqm + i * 16 + l16;
      const float ma = sred[0][0][row], mb = sred[0][1][row];
      const float la = sred[1][0][row], lb = sred[1][1][row];
      const float mn = fmaxf(ma, mb);
      const float l = la * __expf((ma - mn) * 0.125f)
                    + lb * __expf((mb - mn) * 0.125f);
      m_r[i] = mn;
      l_r[i] = 1.f / l;   // inverse denominator
    }
  }

  // ================= loop 2: emit attn + accumulate PV =================
  f32x4 oacc[4][2] = {};
  for (int tc = 0; tc <= tr; ++tc) {
    const int col0 = tc * 128;
    const bool diag = (tc == tr);
    __syncthreads();
#pragma unroll
    for (int c = 0; c < 4; ++c) {
      const int row = wave * 32 + c * 8 + lr;
      gload16(Kp + hoff + (size_t)(col0 + row) * Ec + ((lc ^ lr) << 3),
              &Ks[wave * 32 + c * 8][0]);
    }
    {  // stage V tile transposed: Vt[n][k], full 128k x 64n
      const int kk_ = tid >> 1;
      const int nh  = (tid & 1) * 32;
      const bf16* src = Vh + (size_t)(col0 + kk_) * Ec + nh;
#pragma unroll
      for (int u = 0; u < 4; ++u) {
        uint4 raw = *(const uint4*)(src + u * 8);
        const bf16* pv = (const bf16*)&raw;
#pragma unroll
        for (int jj = 0; jj < 8; ++jj) Vt[nh + u * 8 + jj][kk_] = pv[jj];
      }
    }
    __syncthreads();
    f32x4 sc[4][4] = {};
#pragma unroll
    for (int kk = 0; kk < 2; ++kk) {
      bf16x8 kf[4];
#pragma unroll
      for (int j = 0; j < 4; ++j) {
        const int row = wkn + j * 16 + l16;
        kf[j] = *(const bf16x8*)&Ks[row][((((kk << 2) + quad) ^ (row & 7)) << 3)];
      }
#pragma unroll
      for (int i = 0; i < 4; ++i)
#pragma unroll
        for (int j = 0; j < 4; ++j)
          sc[i][j] = __builtin_amdgcn_mfma_f32_16x16x32_bf16(kf[j], qf[i][kk], sc[i][j], 0, 0, 0);
    }
    // normalize, write final attn (nontemporal float4), write P to LDS (b64)
#pragma unroll
    for (int i = 0; i < 4; ++i) {
      const int row_t = wqm + i * 16 + l16;
      float* orow = out + (size_t)(row0 + row_t) * Sc + col0;
      char* pw = (char*)&Ps[0][0] + row_t * 256;
      const int sw = (row_t & 7) << 4;
#pragma unroll
      for (int j = 0; j < 4; ++j) {
        const int colb = wkn + j * 16 + quad * 4;
        f32x4 p4;
#pragma unroll
        for (int r = 0; r < 4; ++r) {
          float p = __expf((sc[i][j][r] - m_r[i]) * 0.125f) * l_r[i];
          if (diag && (colb + r > row_t)) p = 0.f;
          p4[r] = p;
        }
        __builtin_nontemporal_store(p4, (f32x4*)(orow + colb));
        bf16x4 pb = { (bf16)p4[0], (bf16)p4[1], (bf16)p4[2], (bf16)p4[3] };
        *(bf16x4*)(pw + ((colb * 2) ^ sw)) = pb;
      }
    }
    __syncthreads();
    // PV: O^T = mfma(V^T-frag, P-frag); k chunks of 32 over this 128-col tile
#pragma unroll
    for (int c = 0; c < 4; ++c) {
      bf16x8 vf[2], pf[4];
#pragma unroll
      for (int j2 = 0; j2 < 2; ++j2)
        vf[j2] = *(const bf16x8*)&Vt[wnO + j2 * 16 + l16][c * 32 + quad * 8];
#pragma unroll
      for (int i = 0; i < 4; ++i) {
        const int row = wqm + i * 16 + l16;
        pf[i] = *(const bf16x8*)((const char*)&Ps[0][0] + row * 256 +
                                 ((c * 64 + quad * 16) ^ ((row & 7) << 4)));
      }
#pragma unroll
      for (int i = 0; i < 4; ++i)
#pragma unroll
        for (int j2 = 0; j2 < 2; ++j2)
          oacc[i][j2] = __builtin_amdgcn_mfma_f32_16x16x32_bf16(vf[j2], pf[i], oacc[i][j2], 0, 0, 0);
    }
  }

  // ---- O tile store: O[row = ..+l16][n = ..+quad*4+r] -> b64 stores ----
#pragma unroll
  for (int i = 0; i < 4; ++i) {
    const int grow = row0 + wqm + i * 16 + l16;
#pragma unroll
    for (int j2 = 0; j2 < 2; ++j2) {
      const int ncol = wnO + j2 * 16 + quad * 4;
      bf16x4 ov = { (bf16)oacc[i][j2][0], (bf16)oacc[i][j2][1],
                    (bf16)oacc[i][j2][2], (bf16)oacc[i][j2][3] };
      *(bf16x4*)&Oh[(size_t)grow * Ec + ncol] = ov;
    }
  }

  // ---- zero-fill masked upper tiles (coalesced nontemporal) ----
  {
    const f32x4 z = {0.f, 0.f, 0.f, 0.f};
    const int rsub = tid >> 5, csub = (tid & 31) * 4;
    for (int tc2 = tr + 1; tc2 < 16; ++tc2) {
      const int col0 = tc2 * 128;
#pragma unroll
      for (int rr = 0; rr < 16; ++rr) {
        const int row = row0 + rr * 8 + rsub;
        __builtin_nontemporal_store(z, (f32x4*)&out[(size_t)row * Sc + col0 + csub]);
      }
    }
  }
}

// ---------------------------------------------------------------------------
extern "C" void kernel_launch(void* const* d_in, const int* in_sizes, int n_in,
                              void* d_out, int out_size, void* d_ws, size_t ws_size,
                              hipStream_t stream) {
  (void)in_sizes; (void)n_in; (void)out_size; (void)ws_size;
  const float* q  = (const float*)d_in[0];
  const float* k  = (const float*)d_in[1];
  const float* v  = (const float*)d_in[2];
  const float* wq = (const float*)d_in[3];
  const float* bq = (const float*)d_in[4];
  const float* wk = (const float*)d_in[5];
  const float* bk = (const float*)d_in[6];
  const float* wv = (const float*)d_in[7];
  const float* bv = (const float*)d_in[8];
  const float* wo = (const float*)d_in[9];
  const float* bo = (const float*)d_in[10];
  // causal flag (d_in[11]) is always 1 for this problem; hardcoded.

  float* out  = (float*)d_out;
  float* attn = out + NE;  // [B,H,S,S] fp32

  // bf16 workspace (64 MB, same budget as verified previous version)
  bf16* wsQ = (bf16*)d_ws;
  bf16* wsK = wsQ + NE;
  bf16* wsV = wsK + NE;
  bf16* wsO = wsV + NE;

  // bf16 scratch for converted inputs lives in the attn region (written later
  // by fused_attn, consumed before that by the projection GEMMs).
  bf16* qb  = (bf16*)attn;
  bf16* kb  = qb + NE;
  bf16* vb  = kb + NE;
  bf16* wqb = vb + NE;
  bf16* wkb = wqb + EE;
  bf16* wvb = wkb + EE;

  cvt_all_kernel<<<13824, 256, 0, stream>>>(q, k, v, wq, wk, wv,
                                            qb, kb, vb, wqb, wkb, wvb);

  gemm_bt_bf16<true><<<512, 256, 0, stream>>>(qb, wqb, bq, wsQ);
  gemm_bt_bf16<true><<<512, 256, 0, stream>>>(kb, wkb, bk, wsK);
  gemm_bt_bf16<true><<<512, 256, 0, stream>>>(vb, wvb, bv, wsV);

  fused_attn_kernel<<<1024, 256, 0, stream>>>(wsQ, wsK, wsV, attn, wsO);

  // wo -> bf16 into the (now free) wsQ area, then output projection (fp32 out)
  cvt_one_kernel<<<512, 256, 0, stream>>>(wo, wsQ);
  gemm_bt_bf16<false><<<512, 256, 0, stream>>>(wsO, wsQ, bo, out);
}

// Round 3
// 1386.584 us; speedup vs baseline: 1.2878x; 1.0067x over previous
//
#include <hip/hip_runtime.h>
#include <hip/hip_bf16.h>

// Problem constants: B=4, S=2048, E=1024, H=16, DH=64. causal==1 always.
typedef __bf16 bf16;
typedef __bf16 bf16x2 __attribute__((ext_vector_type(2)));
typedef __bf16 bf16x4 __attribute__((ext_vector_type(4)));
typedef __bf16 bf16x8 __attribute__((ext_vector_type(8)));
typedef float f32x4 __attribute__((ext_vector_type(4)));

constexpr int Bc = 4, Sc = 2048, Ec = 1024, Hc = 16, DHc = 64;
constexpr int MBS = Bc * Sc;              // 8192 rows for all projections
constexpr size_t NE = (size_t)MBS * Ec;   // 8,388,608 elements
constexpr size_t EE = (size_t)Ec * Ec;    // 1,048,576 (weight elems)

// Async global->LDS, 16B per lane, wave-uniform LDS base + lane*16.
__device__ __forceinline__ void gload16(const bf16* g, bf16* l) {
  __builtin_amdgcn_global_load_lds(
      (const __attribute__((address_space(1))) void*)g,
      (__attribute__((address_space(3))) void*)l, 16, 0, 0);
}

// ---------------------------------------------------------------------------
// fp32 -> bf16 converter: q,k,v (4096 blocks each) + wq,wk,wv,wo (512 each)
// ---------------------------------------------------------------------------
__global__ __launch_bounds__(256) void cvt_all_kernel(
    const float* __restrict__ q, const float* __restrict__ k,
    const float* __restrict__ v, const float* __restrict__ wq,
    const float* __restrict__ wk, const float* __restrict__ wv,
    const float* __restrict__ wo,
    bf16* __restrict__ qb, bf16* __restrict__ kb, bf16* __restrict__ vb,
    bf16* __restrict__ wqb, bf16* __restrict__ wkb, bf16* __restrict__ wvb,
    bf16* __restrict__ wob)
{
  const int g = blockIdx.x;  // 12288 big + 2048 small = 14336
  const float* s; bf16* d; size_t off;
  if (g < 12288) {
    const int t = g >> 12;
    s = (t == 0) ? q : (t == 1) ? k : v;
    d = (t == 0) ? qb : (t == 1) ? kb : vb;
    off = (size_t)(g & 4095) * 2048;
  } else {
    const int t = (g - 12288) >> 9;
    s = (t == 0) ? wq : (t == 1) ? wk : (t == 2) ? wv : wo;
    d = (t == 0) ? wqb : (t == 1) ? wkb : (t == 2) ? wvb : wob;
    off = (size_t)((g - 12288) & 511) * 2048;
  }
  const size_t i = off + (size_t)threadIdx.x * 8;
  const float4 a = *(const float4*)&s[i];
  const float4 b = *(const float4*)&s[i + 4];
  bf16x8 o = { (bf16)a.x, (bf16)a.y, (bf16)a.z, (bf16)a.w,
               (bf16)b.x, (bf16)b.y, (bf16)b.z, (bf16)b.w };
  *(bf16x8*)&d[i] = o;
}

// ---------------------------------------------------------------------------
// GEMM core (B-transposed), bf16: C[m,n] = sum_k A[m,k]*W[n,k] + bias[n].
// 128x128 tile, BK=64, 2-phase double-buffered pipeline: STAGE(next) issued
// before compute(cur), ONE barrier per K-step (its implicit vmcnt(0)/lgkmcnt
// drain is the pipeline wait). Swapped MFMA operands -> C row on l16 axis,
// col on quad*4+r axis -> float4/bf16x4 vectorized stores.
// ---------------------------------------------------------------------------
template<bool OUT_BF16>
__device__ __forceinline__ void gemm_core(
    const bf16* __restrict__ A, const bf16* __restrict__ W,
    const float* __restrict__ bias, void* __restrict__ Cout,
    int gg, bf16 (&As)[2][128][64], bf16 (&Ws)[2][128][64])
{
  const int tid  = threadIdx.x;
  const int wave = tid >> 6, lane = tid & 63;
  const int quad = lane >> 4, l16 = lane & 15;
  const int lr = lane >> 3, lc = lane & 7;
  const int wm = (wave & 1) * 64, wn = (wave >> 1) * 64;
  // XCD-chunked: (gg&7)=XCD -> 8-m-tile panel; A panel 2MB + W 2MB fit L2/XCD
  const int m0 = ((gg & 7) * 8 + (gg >> 6)) * 128;
  const int n0 = ((gg >> 3) & 7) * 128;
  f32x4 acc[4][4] = {};

  auto stage = [&](int buf, int k0) {
#pragma unroll
    for (int c = 0; c < 4; ++c) {
      const int row = wave * 32 + c * 8;
      gload16(A + (size_t)(m0 + row + lr) * 1024 + k0 + ((lc ^ lr) << 3),
              &As[buf][row][0]);
      gload16(W + (size_t)(n0 + row + lr) * 1024 + k0 + ((lc ^ lr) << 3),
              &Ws[buf][row][0]);
    }
  };

  stage(0, 0);
  __syncthreads();                       // drains prologue gloads
  for (int t = 0; t < 16; ++t) {
    const int cur = t & 1;
    if (t < 15) stage(cur ^ 1, (t + 1) * 64);   // prefetch flies under MFMA
#pragma unroll
    for (int kk = 0; kk < 2; ++kk) {
      bf16x8 af[4], bg[4];
#pragma unroll
      for (int i = 0; i < 4; ++i) {
        const int row = wm + i * 16 + l16;
        af[i] = *(const bf16x8*)&As[cur][row][((((kk << 2) + quad) ^ (row & 7)) << 3)];
      }
#pragma unroll
      for (int j = 0; j < 4; ++j) {
        const int row = wn + j * 16 + l16;
        bg[j] = *(const bf16x8*)&Ws[cur][row][((((kk << 2) + quad) ^ (row & 7)) << 3)];
      }
#pragma unroll
      for (int i = 0; i < 4; ++i)
#pragma unroll
        for (int j = 0; j < 4; ++j)
          acc[i][j] = __builtin_amdgcn_mfma_f32_16x16x32_bf16(bg[j], af[i], acc[i][j], 0, 0, 0);
    }
    __syncthreads();   // waits this wave's prefetch + all waves' cur reads
  }

  // epilogue: C[m = m0+wm+i*16+l16][n = n0+wn+j*16+quad*4 .. +3]
#pragma unroll
  for (int i = 0; i < 4; ++i) {
    const int row = m0 + wm + i * 16 + l16;
#pragma unroll
    for (int j = 0; j < 4; ++j) {
      const int colb = n0 + wn + j * 16 + quad * 4;
      const float4 bv = *(const float4*)&bias[colb];
      f32x4 v = { acc[i][j][0] + bv.x, acc[i][j][1] + bv.y,
                  acc[i][j][2] + bv.z, acc[i][j][3] + bv.w };
      if constexpr (OUT_BF16) {
        bf16x4 o = { (bf16)v[0], (bf16)v[1], (bf16)v[2], (bf16)v[3] };
        *(bf16x4*)&((bf16*)Cout)[(size_t)row * 1024 + colb] = o;
      } else {
        *(f32x4*)&((float*)Cout)[(size_t)row * 1024 + colb] = v;
      }
    }
  }
}

// Merged Q/K/V projection: blocks [0,512)=Q, [512,1024)=K, [1024,1536)=V.
__global__ __launch_bounds__(256, 2) void proj3_kernel(
    const bf16* __restrict__ qb, const bf16* __restrict__ kb,
    const bf16* __restrict__ vb, const bf16* __restrict__ wqb,
    const bf16* __restrict__ wkb, const bf16* __restrict__ wvb,
    const float* __restrict__ bq, const float* __restrict__ bk,
    const float* __restrict__ bv,
    bf16* __restrict__ Qo, bf16* __restrict__ Ko, bf16* __restrict__ Vo)
{
  __shared__ bf16 As[2][128][64], Ws[2][128][64];
  const int g = blockIdx.x, which = g >> 9, gg = g & 511;
  const bf16* A = (which == 0) ? qb : (which == 1) ? kb : vb;
  const bf16* W = (which == 0) ? wqb : (which == 1) ? wkb : wvb;
  const float* bias = (which == 0) ? bq : (which == 1) ? bk : bv;
  bf16* C = (which == 0) ? Qo : (which == 1) ? Ko : Vo;
  gemm_core<true>(A, W, bias, C, gg, As, Ws);
}

__global__ __launch_bounds__(256, 2) void gemm_out_kernel(
    const bf16* __restrict__ A, const bf16* __restrict__ W,
    const float* __restrict__ bias, float* __restrict__ C)
{
  __shared__ bf16 As[2][128][64], Ws[2][128][64];
  gemm_core<false>(A, W, bias, C, blockIdx.x, As, Ws);
}

// ---------------------------------------------------------------------------
// Fused attention per (bh, 128-row tile), swapped-operand MFMA throughout.
// Loop1 (online m,l): K double-buffered through KPool, prefetch under
//   MFMA+stats, 1 barrier/tile.
// Loop2 (emit attn + PV): 2 barriers/tile; K(tc+1) gload issued after the
//   QK-read barrier (flies under PV); V(tc+1) prefetched into registers
//   (flies under a full iteration); V transposed via paired ds_write_b32.
// ---------------------------------------------------------------------------
__global__ __launch_bounds__(256, 2) void fused_attn_kernel(
    const bf16* __restrict__ Qp, const bf16* __restrict__ Kp,
    const bf16* __restrict__ Vp, float* __restrict__ attn,
    bf16* __restrict__ Op)
{
  // XCD-chunked swizzle: xcd = g&7 owns bh group xcd*8..+7.
  const int g   = blockIdx.x;
  const int idx = g >> 3;
  const int bh  = (g & 7) * 8 + (idx >> 4);
  const int tr  = 15 - (idx & 15);          // heavy (diagonal-rich) first
  const int b = bh >> 4, h = bh & 15;
  const int row0 = tr * 128;
  float* __restrict__ out = attn + (size_t)bh * Sc * Sc;
  const size_t hoff = (size_t)b * Sc * Ec + (size_t)h * DHc;
  const bf16* __restrict__ Vh = Vp + hoff;
  bf16* __restrict__ Oh = Op + hoff;

  __shared__ bf16 KPool[2][8704];   // [0]: Ks; [1]: loop1 K-dbuf / loop2 Vt
  __shared__ bf16 Ps[128 * 128];    // XOR-swizzled P (stages Q at prologue)
  __shared__ float sred[2][2][128];
  bf16* Ks = KPool[0];
  bf16 (*Vt)[136] = (bf16(*)[136])KPool[1];

  const int tid  = threadIdx.x;
  const int wave = tid >> 6, lane = tid & 63;
  const int quad = lane >> 4, l16 = lane & 15;
  const int lr = lane >> 3, lc = lane & 7;
  const int wqm = (wave & 1) * 64;          // Q-row group (QK and PV)
  const int wkn = (wave >> 1) * 64;         // K-col group (QK)
  const int wnO = (wave >> 1) * 32;         // O-col group (PV)

  auto stageK = [&](bf16* dst, int col0_) {
#pragma unroll
    for (int c = 0; c < 4; ++c) {
      const int row = wave * 32 + c * 8;
      gload16(Kp + hoff + (size_t)(col0_ + row + lr) * Ec + ((lc ^ lr) << 3),
              dst + row * 64);
    }
  };

  // ---- prologue: stage Q (into Ps area) + K(0); one barrier; qf to regs ----
#pragma unroll
  for (int c = 0; c < 4; ++c) {
    const int row = wave * 32 + c * 8;
    gload16(Qp + hoff + (size_t)(row0 + row + lr) * Ec + ((lc ^ lr) << 3),
            Ps + row * 64);
  }
  stageK(Ks, 0);
  __syncthreads();
  bf16x8 qf[4][2];
#pragma unroll
  for (int i = 0; i < 4; ++i)
#pragma unroll
    for (int kk = 0; kk < 2; ++kk) {
      const int row = wqm + i * 16 + l16;
      qf[i][kk] = *(const bf16x8*)(Ps + row * 64 +
                                   ((((kk << 2) + quad) ^ (row & 7)) << 3));
    }

  float m_r[4], l_r[4];
#pragma unroll
  for (int i = 0; i < 4; ++i) { m_r[i] = -3.4e38f; l_r[i] = 0.f; }

  // ================= loop 1: online row max / sumexp (K dbuf) ==============
  for (int tc = 0; tc <= tr; ++tc) {
    if (tc < tr) stageK(KPool[(tc & 1) ^ 1], (tc + 1) * 128);  // prefetch
    const bf16* kb_ = KPool[tc & 1];
    f32x4 sc[4][4] = {};
#pragma unroll
    for (int kk = 0; kk < 2; ++kk) {
      bf16x8 kf[4];
#pragma unroll
      for (int j = 0; j < 4; ++j) {
        const int row = wkn + j * 16 + l16;
        kf[j] = *(const bf16x8*)(kb_ + row * 64 +
                                 ((((kk << 2) + quad) ^ (row & 7)) << 3));
      }
#pragma unroll
      for (int i = 0; i < 4; ++i)
#pragma unroll
        for (int j = 0; j < 4; ++j)
          sc[i][j] = __builtin_amdgcn_mfma_f32_16x16x32_bf16(kf[j], qf[i][kk], sc[i][j], 0, 0, 0);
    }
    if (tc == tr) {  // causal mask inside diagonal tile
#pragma unroll
      for (int i = 0; i < 4; ++i) {
        const int row_t = wqm + i * 16 + l16;
#pragma unroll
        for (int j = 0; j < 4; ++j) {
          const int colb = wkn + j * 16 + quad * 4;
#pragma unroll
          for (int r = 0; r < 4; ++r)
            if (colb + r > row_t) sc[i][j][r] = -3.4e38f;
        }
      }
    }
#pragma unroll
    for (int i = 0; i < 4; ++i) {
      float tm = sc[i][0][0];
#pragma unroll
      for (int j = 0; j < 4; ++j)
#pragma unroll
        for (int r = 0; r < 4; ++r) tm = fmaxf(tm, sc[i][j][r]);
      tm = fmaxf(tm, __shfl_xor(tm, 16, 64));   // cross-quad: full 64-col max
      tm = fmaxf(tm, __shfl_xor(tm, 32, 64));
      const float mn = fmaxf(m_r[i], tm);
      float s = 0.f;
#pragma unroll
      for (int j = 0; j < 4; ++j)
#pragma unroll
        for (int r = 0; r < 4; ++r) s += __expf((sc[i][j][r] - mn) * 0.125f);
      s += __shfl_xor(s, 16, 64);
      s += __shfl_xor(s, 32, 64);
      l_r[i] = l_r[i] * __expf((m_r[i] - mn) * 0.125f) + s;
      m_r[i] = mn;
    }
    __syncthreads();   // drains prefetch; all reads of kb_ done
  }

  // ---- loop2 prologue: issue K(0) reload + V(0) reg loads, then merge ----
  const int kp = (tid & 63) * 2;       // k, k+1 pair (V transpose staging)
  const int nh = (tid >> 6) * 16;      // 16-n group per wave
  bf16x8 v0a, v0b, v1a, v1b;
  {
    const bf16* s0 = Vh + (size_t)kp * Ec + nh;
    v0a = *(const bf16x8*)s0;        v0b = *(const bf16x8*)(s0 + 8);
    v1a = *(const bf16x8*)(s0 + Ec); v1b = *(const bf16x8*)(s0 + Ec + 8);
  }
  stageK(Ks, 0);

  {  // merge the two 64-col halves per row
    const int cg = wave >> 1;
    if (quad == 0) {
#pragma unroll
      for (int i = 0; i < 4; ++i) {
        const int row = wqm + i * 16 + l16;
        sred[0][cg][row] = m_r[i];
        sred[1][cg][row] = l_r[i];
      }
    }
    __syncthreads();   // merge barrier; also drains K(0)/V(0) loads
#pragma unroll
    for (int i = 0; i < 4; ++i) {
      const int row = wqm + i * 16 + l16;
      const float ma = sred[0][0][row], mb = sred[0][1][row];
      const float la = sred[1][0][row], lb = sred[1][1][row];
      const float mn = fmaxf(ma, mb);
      const float l = la * __expf((ma - mn) * 0.125f)
                    + lb * __expf((mb - mn) * 0.125f);
      m_r[i] = mn;
      l_r[i] = 1.f / l;   // inverse denominator
    }
  }

  // ================= loop 2: emit attn + accumulate PV =================
  f32x4 oacc[4][2] = {};
  for (int tc = 0; tc <= tr; ++tc) {
    const int col0 = tc * 128;
    const bool diag = (tc == tr);
    __syncthreads();   // A: Vt/Ps free (prev PV done); K(tc) gloads drained
    // write V(tc) regs -> Vt (paired b32, conflict-free), prefetch V(tc+1)
#pragma unroll
    for (int jj = 0; jj < 8; ++jj) {
      bf16x2 w0 = { v0a[jj], v1a[jj] };
      *(bf16x2*)&Vt[nh + jj][kp] = w0;
      bf16x2 w1 = { v0b[jj], v1b[jj] };
      *(bf16x2*)&Vt[nh + jj + 8][kp] = w1;
    }
    if (tc < tr) {
      const bf16* s0 = Vh + (size_t)(col0 + 128 + kp) * Ec + nh;
      v0a = *(const bf16x8*)s0;        v0b = *(const bf16x8*)(s0 + 8);
      v1a = *(const bf16x8*)(s0 + Ec); v1b = *(const bf16x8*)(s0 + Ec + 8);
    }
    // QK on Ks
    f32x4 sc[4][4] = {};
#pragma unroll
    for (int kk = 0; kk < 2; ++kk) {
      bf16x8 kf[4];
#pragma unroll
      for (int j = 0; j < 4; ++j) {
        const int row = wkn + j * 16 + l16;
        kf[j] = *(const bf16x8*)(Ks + row * 64 +
                                 ((((kk << 2) + quad) ^ (row & 7)) << 3));
      }
#pragma unroll
      for (int i = 0; i < 4; ++i)
#pragma unroll
        for (int j = 0; j < 4; ++j)
          sc[i][j] = __builtin_amdgcn_mfma_f32_16x16x32_bf16(kf[j], qf[i][kk], sc[i][j], 0, 0, 0);
    }
    // normalize, write final attn (nontemporal float4), write P to LDS (b64)
#pragma unroll
    for (int i = 0; i < 4; ++i) {
      const int row_t = wqm + i * 16 + l16;
      float* orow = out + (size_t)(row0 + row_t) * Sc + col0;
      char* pw = (char*)Ps + row_t * 256;
      const int sw = (row_t & 7) << 4;
#pragma unroll
      for (int j = 0; j < 4; ++j) {
        const int colb = wkn + j * 16 + quad * 4;
        f32x4 p4;
#pragma unroll
        for (int r = 0; r < 4; ++r) {
          float p = __expf((sc[i][j][r] - m_r[i]) * 0.125f) * l_r[i];
          if (diag && (colb + r > row_t)) p = 0.f;
          p4[r] = p;
        }
        __builtin_nontemporal_store(p4, (f32x4*)(orow + colb));
        bf16x4 pb = { (bf16)p4[0], (bf16)p4[1], (bf16)p4[2], (bf16)p4[3] };
        *(bf16x4*)(pw + ((colb * 2) ^ sw)) = pb;
      }
    }
    __syncthreads();   // C: Ps+Vt visible; all Ks reads done
    if (tc < tr) stageK(Ks, col0 + 128);   // K(tc+1) flies under PV
    // PV: O^T = mfma(V^T-frag, P-frag); 4 k-chunks of 32
#pragma unroll
    for (int c = 0; c < 4; ++c) {
      bf16x8 vf[2], pf[4];
#pragma unroll
      for (int j2 = 0; j2 < 2; ++j2)
        vf[j2] = *(const bf16x8*)&Vt[wnO + j2 * 16 + l16][c * 32 + quad * 8];
#pragma unroll
      for (int i = 0; i < 4; ++i) {
        const int row = wqm + i * 16 + l16;
        pf[i] = *(const bf16x8*)((const char*)Ps + row * 256 +
                                 ((c * 64 + quad * 16) ^ ((row & 7) << 4)));
      }
#pragma unroll
      for (int i = 0; i < 4; ++i)
#pragma unroll
        for (int j2 = 0; j2 < 2; ++j2)
          oacc[i][j2] = __builtin_amdgcn_mfma_f32_16x16x32_bf16(vf[j2], pf[i], oacc[i][j2], 0, 0, 0);
    }
  }

  // ---- O tile store: O[row=..+l16][n=..+quad*4+r] -> b64 stores ----
#pragma unroll
  for (int i = 0; i < 4; ++i) {
    const int grow = row0 + wqm + i * 16 + l16;
#pragma unroll
    for (int j2 = 0; j2 < 2; ++j2) {
      const int ncol = wnO + j2 * 16 + quad * 4;
      bf16x4 ov = { (bf16)oacc[i][j2][0], (bf16)oacc[i][j2][1],
                    (bf16)oacc[i][j2][2], (bf16)oacc[i][j2][3] };
      *(bf16x4*)&Oh[(size_t)grow * Ec + ncol] = ov;
    }
  }

  // ---- zero-fill masked upper tiles (coalesced nontemporal) ----
  {
    const f32x4 z = {0.f, 0.f, 0.f, 0.f};
    const int rsub = tid >> 5, csub = (tid & 31) * 4;
    for (int tc2 = tr + 1; tc2 < 16; ++tc2) {
      const int col0 = tc2 * 128;
#pragma unroll
      for (int rr = 0; rr < 16; ++rr) {
        const int row = row0 + rr * 8 + rsub;
        __builtin_nontemporal_store(z, (f32x4*)&out[(size_t)row * Sc + col0 + csub]);
      }
    }
  }
}

// ---------------------------------------------------------------------------
extern "C" void kernel_launch(void* const* d_in, const int* in_sizes, int n_in,
                              void* d_out, int out_size, void* d_ws, size_t ws_size,
                              hipStream_t stream) {
  (void)in_sizes; (void)n_in; (void)out_size; (void)ws_size;
  const float* q  = (const float*)d_in[0];
  const float* k  = (const float*)d_in[1];
  const float* v  = (const float*)d_in[2];
  const float* wq = (const float*)d_in[3];
  const float* bq = (const float*)d_in[4];
  const float* wk = (const float*)d_in[5];
  const float* bk = (const float*)d_in[6];
  const float* wv = (const float*)d_in[7];
  const float* bv = (const float*)d_in[8];
  const float* wo = (const float*)d_in[9];
  const float* bo = (const float*)d_in[10];
  // causal flag (d_in[11]) is always 1 for this problem; hardcoded.

  float* out  = (float*)d_out;
  float* attn = out + NE;  // [B,H,S,S] fp32

  // bf16 workspace (69 MB)
  bf16* wsQ = (bf16*)d_ws;
  bf16* wsK = wsQ + NE;
  bf16* wsV = wsK + NE;
  bf16* wsO = wsV + NE;
  bf16* wob = wsO + NE;    // wo in bf16 (read after fused_attn -> keep in ws)

  // bf16 scratch for converted inputs lives in the attn region (written later
  // by fused_attn, consumed before that by the projection GEMMs).
  bf16* qb  = (bf16*)attn;
  bf16* kb  = qb + NE;
  bf16* vb  = kb + NE;
  bf16* wqb = vb + NE;
  bf16* wkb = wqb + EE;
  bf16* wvb = wkb + EE;

  cvt_all_kernel<<<14336, 256, 0, stream>>>(q, k, v, wq, wk, wv, wo,
                                            qb, kb, vb, wqb, wkb, wvb, wob);

  proj3_kernel<<<1536, 256, 0, stream>>>(qb, kb, vb, wqb, wkb, wvb,
                                         bq, bk, bv, wsQ, wsK, wsV);

  fused_attn_kernel<<<1024, 256, 0, stream>>>(wsQ, wsK, wsV, attn, wsO);

  gemm_out_kernel<<<512, 256, 0, stream>>>(wsO, wob, bo, out);
}